// Round 1
// baseline (638.099 us; speedup 1.0000x reference)
//
#include <hip/hip_runtime.h>

// Problem constants
#define BB 4
#define NT_TOK 2048
#define DD 1024
#define EE 16
#define HH 4096
#define CAP 160
#define NTOK (BB * NT_TOK)      // 8192 tokens
#define MROWS (BB * CAP)        // 640 rows per expert

typedef __attribute__((ext_vector_type(4))) float floatx4;
typedef __attribute__((ext_vector_type(8))) short short8;

__device__ __forceinline__ ushort f2bf(float f) {
  union { float f; unsigned u; } v; v.f = f;
  unsigned u = v.u;
  return (ushort)((u + 0x7FFFu + ((u >> 16) & 1u)) >> 16);   // RNE
}

// ---------------------------------------------------------------------------
// Kernel 1: gating. One wave per token. Computes 16 logits, softmax, top-2,
// normalized gates, keep_2 (noise test), density sums for aux loss.
// ---------------------------------------------------------------------------
__global__ __launch_bounds__(256)
void k_gating(const float* __restrict__ x, const float* __restrict__ wg,
              const float* __restrict__ noise,
              int* __restrict__ idx1, int* __restrict__ idx2,
              float* __restrict__ g1, float* __restrict__ g2,
              int* __restrict__ pos1, int* __restrict__ pos2,
              float* __restrict__ dp, float* __restrict__ d1)
{
  __shared__ float s_dp[EE];
  __shared__ float s_d1[EE];
  const int tid = threadIdx.x, lane = tid & 63, wave = tid >> 6;
  if (tid < EE) { s_dp[tid] = 0.f; s_d1[tid] = 0.f; }
  __syncthreads();

  const int t = blockIdx.x * 4 + wave;      // token id (b*N+n)
  const int b = t / NT_TOK;

  float acc[EE];
#pragma unroll
  for (int e = 0; e < EE; ++e) acc[e] = 0.f;

  const float* xr = x + (size_t)t * DD;
#pragma unroll 4
  for (int i = 0; i < DD / 64; ++i) {
    const int d = i * 64 + lane;
    const float xv = xr[d];
    const float4* wr = (const float4*)(wg + (size_t)d * EE);
#pragma unroll
    for (int q = 0; q < 4; ++q) {
      const float4 w4 = wr[q];
      acc[q * 4 + 0] += xv * w4.x;
      acc[q * 4 + 1] += xv * w4.y;
      acc[q * 4 + 2] += xv * w4.z;
      acc[q * 4 + 3] += xv * w4.w;
    }
  }
  // butterfly reduce all 16 partial sums across the 64 lanes
#pragma unroll
  for (int off = 32; off >= 1; off >>= 1)
#pragma unroll
    for (int e = 0; e < EE; ++e) acc[e] += __shfl_xor(acc[e], off);

  // softmax (all lanes redundantly)
  float mx = acc[0];
#pragma unroll
  for (int e = 1; e < EE; ++e) mx = fmaxf(mx, acc[e]);
  float g[EE], s = 0.f;
#pragma unroll
  for (int e = 0; e < EE; ++e) { g[e] = expf(acc[e] - mx); s += g[e]; }
  const float inv = 1.f / s;
#pragma unroll
  for (int e = 0; e < EE; ++e) g[e] *= inv;

  // top-1 (first max), top-2 over the rest (first max)
  int i1 = 0; float v1 = g[0];
#pragma unroll
  for (int e = 1; e < EE; ++e) if (g[e] > v1) { v1 = g[e]; i1 = e; }
  int i2 = -1; float v2 = -1.f;
#pragma unroll
  for (int e = 0; e < EE; ++e) if (e != i1 && g[e] > v2) { v2 = g[e]; i2 = e; }

  const float denom = v1 + v2 + 1e-9f;
  const float g1n = v1 / denom, g2n = v2 / denom;
  const bool keep2 = noise[t] < (g2n / 0.2f);

  if (lane == 0) {
    idx1[t] = i1;
    idx2[t] = keep2 ? i2 : -1;
    g1[t] = g1n; g2[t] = g2n;
    pos1[t] = -1; pos2[t] = -1;      // scan kernel overwrites kept tokens
  }
  if (lane < EE) atomicAdd(&s_dp[lane], g[lane]);    // raw softmax gates
  if (lane == 0) atomicAdd(&s_d1[i1], 1.f);          // pre-capacity mask_1
  __syncthreads();
  if (tid < EE) {
    atomicAdd(&dp[b * EE + tid], s_dp[tid]);
    atomicAdd(&d1[b * EE + tid], s_d1[tid]);
  }
}

// ---------------------------------------------------------------------------
// Kernel 2: per-(b,e) exclusive-cumsum scan via ballot/popcount.
// Primary pass assigns slots [0,count1); secondary continues at count1.
// ---------------------------------------------------------------------------
__global__ __launch_bounds__(64)
void k_scan(const int* __restrict__ idx1, const int* __restrict__ idx2,
            int* __restrict__ pos1, int* __restrict__ pos2,
            int* __restrict__ slot_tok)
{
  const int b = (int)blockIdx.x >> 4;
  const int e = (int)blockIdx.x & 15;
  const int lane = threadIdx.x;
  const unsigned long long lm = (1ull << lane) - 1ull;
  int* st = slot_tok + ((size_t)e * BB + b) * CAP;

  int v[NT_TOK / 64];
#pragma unroll
  for (int c = 0; c < NT_TOK / 64; ++c) v[c] = idx1[b * NT_TOK + c * 64 + lane];
  int base = 0;
  for (int c = 0; c < NT_TOK / 64; ++c) {
    const bool m = (v[c] == e);
    const unsigned long long bal = __ballot(m);
    if (m) {
      const int p = base + __popcll(bal & lm);
      if (p < CAP) { const int n = c * 64 + lane; pos1[b * NT_TOK + n] = p; st[p] = n; }
    }
    base += __popcll(bal);
  }
  const int count1 = base < CAP ? base : CAP;   // == sum of truncated mask_1

#pragma unroll
  for (int c = 0; c < NT_TOK / 64; ++c) v[c] = idx2[b * NT_TOK + c * 64 + lane];
  base = count1;
  for (int c = 0; c < NT_TOK / 64; ++c) {
    const bool m = (v[c] == e);
    const unsigned long long bal = __ballot(m);
    if (m) {
      const int p = base + __popcll(bal & lm);
      if (p < CAP) { const int n = c * 64 + lane; pos2[b * NT_TOK + n] = p; st[p] = n; }
    }
    base += __popcll(bal);
  }
  const int used = base < CAP ? base : CAP;
  for (int p = used + lane; p < CAP; p += 64) st[p] = -1;  // empty slots
}

// ---------------------------------------------------------------------------
// Kernel 3: gather x rows into bf16 expert-input matrix ei[e][b*CAP+c][D].
// ---------------------------------------------------------------------------
__global__ __launch_bounds__(256)
void k_gather(const float* __restrict__ x, const int* __restrict__ slot_tok,
              ushort* __restrict__ ei)
{
  const int s = blockIdx.x;               // e*640 + b*160 + c
  const int tid = threadIdx.x;
  const int r = s % MROWS;
  const int b = r / CAP;
  const int tok = slot_tok[s];
  ushort4 o;
  if (tok >= 0) {
    const float4 v = *(const float4*)(x + ((size_t)b * NT_TOK + tok) * DD + tid * 4);
    o.x = f2bf(v.x); o.y = f2bf(v.y); o.z = f2bf(v.z); o.w = f2bf(v.w);
  } else {
    o.x = 0; o.y = 0; o.z = 0; o.w = 0;
  }
  *(ushort4*)(ei + (size_t)s * DD + tid * 4) = o;
}

// ---------------------------------------------------------------------------
// Grouped expert GEMM: C[e] = A[e] (bf16 MROWSxK) * W[e] (fp32 KxNC, converted
// inline to bf16). 128x128 tile, BK=32, 4 waves, 16x16x32 MFMA.
// RELU_BF16: relu + bf16 store (GEMM1) else fp32 store (GEMM2).
// ---------------------------------------------------------------------------
template<int K, int NC, bool RELU_BF16>
__global__ __launch_bounds__(256)
void expert_gemm(const ushort* __restrict__ A, const float* __restrict__ W,
                 ushort* __restrict__ Cb, float* __restrict__ Cf)
{
  constexpr int MT = MROWS / 128;          // 5
  constexpr int NTl = NC / 128;
  constexpr int nwg = EE * MT * NTl;       // divisible by 8
  int wg = ((int)blockIdx.x & 7) * (nwg / 8) + ((int)blockIdx.x >> 3);  // XCD swizzle
  const int mt = wg % MT; wg /= MT;        // mt fastest: M-tiles share W panel in L2
  const int nt = wg % NTl;
  const int e  = wg / NTl;
  const int m0 = mt * 128, n0 = nt * 128;

  __shared__ ushort As[128 * 32];
  __shared__ ushort Bs[128 * 32];          // transposed: [n][k], contiguous k

  const int tid = threadIdx.x;
  const int lane = tid & 63;
  const int wr = (tid >> 6) >> 1;
  const int wc = (tid >> 6) & 1;
  const int fr = lane & 15, fq = lane >> 4;

  const ushort* Ae = A + (size_t)e * MROWS * K;
  const float*  We = W + (size_t)e * K * NC;

  const int arow = tid >> 1;               // 0..127
  const int acol = (tid & 1) * 16;         // ushort offset (two 16B chunks)
  const int bn4 = (tid & 31) * 4;          // n offset
  const int bk4 = (tid >> 5) * 4;          // k offset

  floatx4 acc[4][4];
#pragma unroll
  for (int m = 0; m < 4; ++m)
#pragma unroll
    for (int n = 0; n < 4; ++n) acc[m][n] = (floatx4){0.f, 0.f, 0.f, 0.f};

  for (int kt = 0; kt < K / 32; ++kt) {
    // global loads into registers (A bf16, W fp32)
    const uint4* ga = (const uint4*)(Ae + (size_t)(m0 + arow) * K + kt * 32 + acol);
    const uint4 a0 = ga[0];
    const uint4 a1 = ga[1];
    float wq[4][4];
#pragma unroll
    for (int kk = 0; kk < 4; ++kk) {
      const float4 f = *(const float4*)(We + (size_t)(kt * 32 + bk4 + kk) * NC + n0 + bn4);
      wq[kk][0] = f.x; wq[kk][1] = f.y; wq[kk][2] = f.z; wq[kk][3] = f.w;
    }

    __syncthreads();                       // prior iter's LDS reads done
    *(uint4*)&As[arow * 32 + acol]     = a0;
    *(uint4*)&As[arow * 32 + acol + 8] = a1;
#pragma unroll
    for (int nn = 0; nn < 4; ++nn) {       // transpose + fp32->bf16
      uint2 p;
      p.x = (uint)f2bf(wq[0][nn]) | ((uint)f2bf(wq[1][nn]) << 16);
      p.y = (uint)f2bf(wq[2][nn]) | ((uint)f2bf(wq[3][nn]) << 16);
      *(uint2*)&Bs[(bn4 + nn) * 32 + bk4] = p;
    }
    __syncthreads();

    short8 af[4], bf[4];
#pragma unroll
    for (int m = 0; m < 4; ++m)
      af[m] = *(const short8*)&As[(wr * 64 + m * 16 + fr) * 32 + fq * 8];
#pragma unroll
    for (int n = 0; n < 4; ++n)
      bf[n] = *(const short8*)&Bs[(wc * 64 + n * 16 + fr) * 32 + fq * 8];
#pragma unroll
    for (int m = 0; m < 4; ++m)
#pragma unroll
      for (int n = 0; n < 4; ++n)
        acc[m][n] = __builtin_amdgcn_mfma_f32_16x16x32_bf16(af[m], bf[n], acc[m][n], 0, 0, 0);
  }

  // epilogue: C/D layout col=lane&15, row=(lane>>4)*4+j  [m89-verified]
#pragma unroll
  for (int m = 0; m < 4; ++m) {
    const int row0 = m0 + wr * 64 + m * 16 + fq * 4;
#pragma unroll
    for (int n = 0; n < 4; ++n) {
      const int col = n0 + wc * 64 + n * 16 + fr;
#pragma unroll
      for (int j = 0; j < 4; ++j) {
        const size_t ci = ((size_t)e * MROWS + row0 + j) * NC + col;
        if constexpr (RELU_BF16) Cb[ci] = f2bf(fmaxf(acc[m][n][j], 0.f));
        else                     Cf[ci] = acc[m][n][j];
      }
    }
  }
}

// ---------------------------------------------------------------------------
// Kernel 6: combine. out[b,n,:] = g1*eo[e1][b*CAP+p1] + g2*eo[e2][b*CAP+p2]
// ---------------------------------------------------------------------------
__global__ __launch_bounds__(256)
void k_combine(const float* __restrict__ eo,
               const int* __restrict__ idx1, const int* __restrict__ idx2,
               const float* __restrict__ g1, const float* __restrict__ g2,
               const int* __restrict__ pos1, const int* __restrict__ pos2,
               float* __restrict__ out)
{
  const int t = blockIdx.x, tid = threadIdx.x;
  const int b = t / NT_TOK;
  float r0 = 0.f, r1 = 0.f, r2 = 0.f, r3 = 0.f;
  const int p1 = pos1[t];
  if (p1 >= 0) {
    const float g = g1[t];
    const float4 v = *(const float4*)(eo + ((size_t)idx1[t] * MROWS + b * CAP + p1) * DD + tid * 4);
    r0 += g * v.x; r1 += g * v.y; r2 += g * v.z; r3 += g * v.w;
  }
  const int p2 = pos2[t];
  if (p2 >= 0) {
    const float g = g2[t];
    const float4 v = *(const float4*)(eo + ((size_t)idx2[t] * MROWS + b * CAP + p2) * DD + tid * 4);
    r0 += g * v.x; r1 += g * v.y; r2 += g * v.z; r3 += g * v.w;
  }
  float4 o; o.x = r0; o.y = r1; o.z = r2; o.w = r3;
  *(float4*)(out + (size_t)t * DD + tid * 4) = o;
}

// ---------------------------------------------------------------------------
// Kernel 7: aux loss. loss = mean_{b,e}(dp/N * d1/N) * E*E * 0.01
// ---------------------------------------------------------------------------
__global__ __launch_bounds__(64)
void k_loss(const float* __restrict__ dens, float* __restrict__ out_loss)
{
  const int lane = threadIdx.x;            // 64 = B*E pairs
  float v = (dens[lane] * (1.f / 2048.f)) * (dens[64 + lane] * (1.f / 2048.f));
#pragma unroll
  for (int off = 32; off >= 1; off >>= 1) v += __shfl_xor(v, off);
  if (lane == 0) out_loss[0] = (v / 64.f) * 256.f * 0.01f;
}

// ---------------------------------------------------------------------------
extern "C" void kernel_launch(void* const* d_in, const int* in_sizes, int n_in,
                              void* d_out, int out_size, void* d_ws, size_t ws_size,
                              hipStream_t stream)
{
  const float* x     = (const float*)d_in[0];
  const float* wgate = (const float*)d_in[1];
  const float* w1    = (const float*)d_in[2];
  const float* w2    = (const float*)d_in[3];
  const float* noise = (const float*)d_in[4];
  float* out = (float*)d_out;

  size_t off = 0;
  char* wsb = (char*)d_ws;
  auto alloc = [&](size_t bytes) -> void* {
    void* p = wsb + off;
    off += (bytes + 255) & ~(size_t)255;
    return p;
  };
  ushort* ei  = (ushort*)alloc((size_t)EE * MROWS * DD * 2);   // 20 MB
  ushort* hid = (ushort*)alloc((size_t)EE * MROWS * HH * 2);   // 80 MB
  float*  eo  = (float*) alloc((size_t)EE * MROWS * DD * 4);   // 40 MB
  int*   idx1 = (int*)  alloc((size_t)NTOK * 4);
  int*   idx2 = (int*)  alloc((size_t)NTOK * 4);
  float* g1   = (float*)alloc((size_t)NTOK * 4);
  float* g2   = (float*)alloc((size_t)NTOK * 4);
  int*   pos1 = (int*)  alloc((size_t)NTOK * 4);
  int*   pos2 = (int*)  alloc((size_t)NTOK * 4);
  int* slot_tok = (int*)alloc((size_t)EE * BB * CAP * 4);
  float* dens = (float*)alloc(128 * 4);    // [0:64)=density_proxy, [64:128)=density_1

  hipMemsetAsync(dens, 0, 128 * 4, stream);
  k_gating<<<NTOK / 4, 256, 0, stream>>>(x, wgate, noise, idx1, idx2, g1, g2,
                                         pos1, pos2, dens, dens + 64);
  k_scan<<<BB * EE, 64, 0, stream>>>(idx1, idx2, pos1, pos2, slot_tok);
  k_gather<<<EE * MROWS, 256, 0, stream>>>(x, slot_tok, ei);
  expert_gemm<DD, HH, true ><<<EE * (MROWS / 128) * (HH / 128), 256, 0, stream>>>(ei,  w1, hid, nullptr);
  expert_gemm<HH, DD, false><<<EE * (MROWS / 128) * (DD / 128), 256, 0, stream>>>(hid, w2, nullptr, eo);
  k_combine<<<NTOK, 256, 0, stream>>>(eo, idx1, idx2, g1, g2, pos1, pos2, out);
  k_loss<<<1, 64, 0, stream>>>(dens, out + (size_t)NTOK * DD);
}

// Round 2
// 447.019 us; speedup vs baseline: 1.4275x; 1.4275x over previous
//
#include <hip/hip_runtime.h>

// Problem constants
#define BB 4
#define NT_TOK 2048
#define DD 1024
#define EE 16
#define HH 4096
#define CAP 160
#define NTOK (BB * NT_TOK)      // 8192 tokens
#define MROWS (BB * CAP)        // 640 rows per expert

typedef __attribute__((ext_vector_type(4))) float floatx4;
typedef __attribute__((ext_vector_type(8))) short short8;

__device__ __forceinline__ ushort f2bf(float f) {
  union { float f; unsigned u; } v; v.f = f;
  unsigned u = v.u;
  return (ushort)((u + 0x7FFFu + ((u >> 16) & 1u)) >> 16);   // RNE
}

__device__ __forceinline__ uint cvt_pk_bf16(float lo, float hi) {
  uint r;
  asm("v_cvt_pk_bf16_f32 %0, %1, %2" : "=v"(r) : "v"(lo), "v"(hi));
  return r;
}

// ---------------------------------------------------------------------------
// Kernel 1: gating. One wave per token. 16 logits, softmax, top-2, keep_2,
// density sums for aux loss.
// ---------------------------------------------------------------------------
__global__ __launch_bounds__(256)
void k_gating(const float* __restrict__ x, const float* __restrict__ wg,
              const float* __restrict__ noise,
              int* __restrict__ idx1, int* __restrict__ idx2,
              float* __restrict__ g1, float* __restrict__ g2,
              int* __restrict__ pos1, int* __restrict__ pos2,
              float* __restrict__ dp, float* __restrict__ d1)
{
  __shared__ float s_dp[EE];
  __shared__ float s_d1[EE];
  const int tid = threadIdx.x, lane = tid & 63, wave = tid >> 6;
  if (tid < EE) { s_dp[tid] = 0.f; s_d1[tid] = 0.f; }
  __syncthreads();

  const int t = blockIdx.x * 4 + wave;      // token id (b*N+n)
  const int b = t / NT_TOK;

  float acc[EE];
#pragma unroll
  for (int e = 0; e < EE; ++e) acc[e] = 0.f;

  const float* xr = x + (size_t)t * DD;
#pragma unroll 4
  for (int i = 0; i < DD / 64; ++i) {
    const int d = i * 64 + lane;
    const float xv = xr[d];
    const float4* wr = (const float4*)(wg + (size_t)d * EE);
#pragma unroll
    for (int q = 0; q < 4; ++q) {
      const float4 w4 = wr[q];
      acc[q * 4 + 0] += xv * w4.x;
      acc[q * 4 + 1] += xv * w4.y;
      acc[q * 4 + 2] += xv * w4.z;
      acc[q * 4 + 3] += xv * w4.w;
    }
  }
#pragma unroll
  for (int off = 32; off >= 1; off >>= 1)
#pragma unroll
    for (int e = 0; e < EE; ++e) acc[e] += __shfl_xor(acc[e], off);

  float mx = acc[0];
#pragma unroll
  for (int e = 1; e < EE; ++e) mx = fmaxf(mx, acc[e]);
  float g[EE], s = 0.f;
#pragma unroll
  for (int e = 0; e < EE; ++e) { g[e] = expf(acc[e] - mx); s += g[e]; }
  const float inv = 1.f / s;
#pragma unroll
  for (int e = 0; e < EE; ++e) g[e] *= inv;

  int i1 = 0; float v1 = g[0];
#pragma unroll
  for (int e = 1; e < EE; ++e) if (g[e] > v1) { v1 = g[e]; i1 = e; }
  int i2 = -1; float v2 = -1.f;
#pragma unroll
  for (int e = 0; e < EE; ++e) if (e != i1 && g[e] > v2) { v2 = g[e]; i2 = e; }

  const float denom = v1 + v2 + 1e-9f;
  const float g1n = v1 / denom, g2n = v2 / denom;
  const bool keep2 = noise[t] < (g2n / 0.2f);

  if (lane == 0) {
    idx1[t] = i1;
    idx2[t] = keep2 ? i2 : -1;
    g1[t] = g1n; g2[t] = g2n;
    pos1[t] = -1; pos2[t] = -1;
  }
  if (lane < EE) atomicAdd(&s_dp[lane], g[lane]);
  if (lane == 0) atomicAdd(&s_d1[i1], 1.f);
  __syncthreads();
  if (tid < EE) {
    atomicAdd(&dp[b * EE + tid], s_dp[tid]);
    atomicAdd(&d1[b * EE + tid], s_d1[tid]);
  }
}

// ---------------------------------------------------------------------------
// Kernel 2: per-(b,e) exclusive-cumsum scan via ballot/popcount.
// ---------------------------------------------------------------------------
__global__ __launch_bounds__(64)
void k_scan(const int* __restrict__ idx1, const int* __restrict__ idx2,
            int* __restrict__ pos1, int* __restrict__ pos2,
            int* __restrict__ slot_tok)
{
  const int b = (int)blockIdx.x >> 4;
  const int e = (int)blockIdx.x & 15;
  const int lane = threadIdx.x;
  const unsigned long long lm = (1ull << lane) - 1ull;
  int* st = slot_tok + ((size_t)e * BB + b) * CAP;

  int v[NT_TOK / 64];
#pragma unroll
  for (int c = 0; c < NT_TOK / 64; ++c) v[c] = idx1[b * NT_TOK + c * 64 + lane];
  int base = 0;
  for (int c = 0; c < NT_TOK / 64; ++c) {
    const bool m = (v[c] == e);
    const unsigned long long bal = __ballot(m);
    if (m) {
      const int p = base + __popcll(bal & lm);
      if (p < CAP) { const int n = c * 64 + lane; pos1[b * NT_TOK + n] = p; st[p] = n; }
    }
    base += __popcll(bal);
  }
  const int count1 = base < CAP ? base : CAP;

#pragma unroll
  for (int c = 0; c < NT_TOK / 64; ++c) v[c] = idx2[b * NT_TOK + c * 64 + lane];
  base = count1;
  for (int c = 0; c < NT_TOK / 64; ++c) {
    const bool m = (v[c] == e);
    const unsigned long long bal = __ballot(m);
    if (m) {
      const int p = base + __popcll(bal & lm);
      if (p < CAP) { const int n = c * 64 + lane; pos2[b * NT_TOK + n] = p; st[p] = n; }
    }
    base += __popcll(bal);
  }
  const int used = base < CAP ? base : CAP;
  for (int p = used + lane; p < CAP; p += 64) st[p] = -1;
}

// ---------------------------------------------------------------------------
// Kernel 3: gather x rows into bf16 expert-input matrix ei[e][b*CAP+c][D].
// ---------------------------------------------------------------------------
__global__ __launch_bounds__(256)
void k_gather(const float* __restrict__ x, const int* __restrict__ slot_tok,
              ushort* __restrict__ ei)
{
  const int s = blockIdx.x;               // e*640 + b*160 + c
  const int tid = threadIdx.x;
  const int r = s % MROWS;
  const int b = r / CAP;
  const int tok = slot_tok[s];
  ushort4 o;
  if (tok >= 0) {
    const float4 v = *(const float4*)(x + ((size_t)b * NT_TOK + tok) * DD + tid * 4);
    o.x = f2bf(v.x); o.y = f2bf(v.y); o.z = f2bf(v.z); o.w = f2bf(v.w);
  } else {
    o.x = 0; o.y = 0; o.z = 0; o.w = 0;
  }
  *(ushort4*)(ei + (size_t)s * DD + tid * 4) = o;
}

// ---------------------------------------------------------------------------
// Grouped expert GEMM: C[e] = A[e] (bf16 MROWSxK) * W[e] (fp32 KxNC, cvt_pk to
// bf16 in-flight). 128x128 tile, BK=32, 4 waves, 16x16x32 MFMA.
// Double-buffered LDS, one barrier per K-step, XOR-swizzled tiles:
//   16B chunk c of row r lives at r*64 + (c ^ ((r>>1)&3))*16 bytes.
// Verified: every 8-lane group of the b128 reads/writes hits 8 distinct
// bank-quads (B-transpose ds_write_b64 has a residual 4-way).
// ---------------------------------------------------------------------------
template<int K, int NC, bool RELU_BF16>
__global__ __launch_bounds__(256)
void expert_gemm(const ushort* __restrict__ A, const float* __restrict__ W,
                 ushort* __restrict__ Cb, float* __restrict__ Cf)
{
  constexpr int MT = MROWS / 128;          // 5
  constexpr int NTl = NC / 128;
  constexpr int nwg = EE * MT * NTl;       // divisible by 8
  constexpr int NKT = K / 32;
  int wg = ((int)blockIdx.x & 7) * (nwg / 8) + ((int)blockIdx.x >> 3);  // XCD swizzle
  const int mt = wg % MT; wg /= MT;        // mt fastest: M-tiles share W panel in L2
  const int nt = wg % NTl;
  const int e  = wg / NTl;
  const int m0 = mt * 128, n0 = nt * 128;

  __shared__ ushort As[2][128 * 32];
  __shared__ ushort Bs[2][128 * 32];       // transposed: [n][k]

  const int tid = threadIdx.x;
  const int lane = tid & 63;
  const int wr = (tid >> 6) >> 1;
  const int wc = (tid >> 6) & 1;
  const int fr = lane & 15, fq = lane >> 4;

  const ushort* Ae = A + (size_t)e * MROWS * K;
  const float*  We = W + (size_t)e * K * NC;

  const int arow = tid >> 1;               // 0..127
  const int acol = (tid & 1) * 16;         // ushort offset
  const int bn4 = (tid & 31) * 4;          // n offset
  const int bk4 = (tid >> 5) * 4;          // k offset

  // swizzled LDS write offsets (ushort units)
  const int ac0 = (tid & 1) * 2;
  const int aswz0 = arow * 32 + ((ac0       ^ ((arow >> 1) & 3)) << 3);
  const int aswz1 = arow * 32 + (((ac0 + 1) ^ ((arow >> 1) & 3)) << 3);
  const int bchunk = (tid >> 6);           // (tid>>5)>>1
  const int bh = ((tid >> 5) & 1) * 4;
  // swizzled read chunk (independent of m/n since 16-row step ≡ 0 mod 4 rows)
  const int cswr = (fq ^ ((fr >> 1) & 3)) << 3;

  const ushort* Arow = Ae + (size_t)(m0 + arow) * K + acol;
  const float*  Wcol = We + n0 + bn4;

  floatx4 acc[4][4];
#pragma unroll
  for (int m = 0; m < 4; ++m)
#pragma unroll
    for (int n = 0; n < 4; ++n) acc[m][n] = (floatx4){0.f, 0.f, 0.f, 0.f};

  uint4 ra0, ra1;
  float wq[4][4];

  auto issue_loads = [&](int kt) {
    const uint4* ga = (const uint4*)(Arow + kt * 32);
    ra0 = ga[0];
    ra1 = ga[1];
#pragma unroll
    for (int kk = 0; kk < 4; ++kk) {
      const float4 f = *(const float4*)(Wcol + (size_t)(kt * 32 + bk4 + kk) * NC);
      wq[kk][0] = f.x; wq[kk][1] = f.y; wq[kk][2] = f.z; wq[kk][3] = f.w;
    }
  };
  auto write_lds = [&](int buf) {
    ushort* as_ = As[buf];
    ushort* bs_ = Bs[buf];
    *(uint4*)&as_[aswz0] = ra0;
    *(uint4*)&as_[aswz1] = ra1;
#pragma unroll
    for (int nn = 0; nn < 4; ++nn) {
      const int row = bn4 + nn;
      uint2 p;
      p.x = cvt_pk_bf16(wq[0][nn], wq[1][nn]);
      p.y = cvt_pk_bf16(wq[2][nn], wq[3][nn]);
      *(uint2*)&bs_[row * 32 + ((bchunk ^ ((row >> 1) & 3)) << 3) + bh] = p;
    }
  };

  // prologue
  issue_loads(0);
  write_lds(0);
  __syncthreads();

  for (int kt = 0; kt < NKT; ++kt) {
    const int cur = kt & 1;
    const bool more = (kt + 1 < NKT);
    if (more) issue_loads(kt + 1);         // in flight across the MFMA phase

    const ushort* as_ = As[cur];
    const ushort* bs_ = Bs[cur];
    short8 af[4], bfr[4];
#pragma unroll
    for (int m = 0; m < 4; ++m)
      af[m] = *(const short8*)&as_[(wr * 64 + m * 16 + fr) * 32 + cswr];
#pragma unroll
    for (int n = 0; n < 4; ++n)
      bfr[n] = *(const short8*)&bs_[(wc * 64 + n * 16 + fr) * 32 + cswr];
#pragma unroll
    for (int m = 0; m < 4; ++m)
#pragma unroll
      for (int n = 0; n < 4; ++n)
        acc[m][n] = __builtin_amdgcn_mfma_f32_16x16x32_bf16(af[m], bfr[n], acc[m][n], 0, 0, 0);

    if (more) {
      write_lds(cur ^ 1);                  // vmcnt wait lands here, not before MFMA
      __syncthreads();                     // single barrier per K-step
    }
  }

  // epilogue: C/D layout col=lane&15, row=(lane>>4)*4+j  [m89-verified]
#pragma unroll
  for (int m = 0; m < 4; ++m) {
    const int row0 = m0 + wr * 64 + m * 16 + fq * 4;
#pragma unroll
    for (int n = 0; n < 4; ++n) {
      const int col = n0 + wc * 64 + n * 16 + fr;
#pragma unroll
      for (int j = 0; j < 4; ++j) {
        const size_t ci = ((size_t)e * MROWS + row0 + j) * NC + col;
        if constexpr (RELU_BF16) Cb[ci] = f2bf(fmaxf(acc[m][n][j], 0.f));
        else                     Cf[ci] = acc[m][n][j];
      }
    }
  }
}

// ---------------------------------------------------------------------------
// Kernel 6: combine. out[b,n,:] = g1*eo[e1][b*CAP+p1] + g2*eo[e2][b*CAP+p2]
// ---------------------------------------------------------------------------
__global__ __launch_bounds__(256)
void k_combine(const float* __restrict__ eo,
               const int* __restrict__ idx1, const int* __restrict__ idx2,
               const float* __restrict__ g1, const float* __restrict__ g2,
               const int* __restrict__ pos1, const int* __restrict__ pos2,
               float* __restrict__ out)
{
  const int t = blockIdx.x, tid = threadIdx.x;
  const int b = t / NT_TOK;
  float r0 = 0.f, r1 = 0.f, r2 = 0.f, r3 = 0.f;
  const int p1 = pos1[t];
  if (p1 >= 0) {
    const float g = g1[t];
    const float4 v = *(const float4*)(eo + ((size_t)idx1[t] * MROWS + b * CAP + p1) * DD + tid * 4);
    r0 += g * v.x; r1 += g * v.y; r2 += g * v.z; r3 += g * v.w;
  }
  const int p2 = pos2[t];
  if (p2 >= 0) {
    const float g = g2[t];
    const float4 v = *(const float4*)(eo + ((size_t)idx2[t] * MROWS + b * CAP + p2) * DD + tid * 4);
    r0 += g * v.x; r1 += g * v.y; r2 += g * v.z; r3 += g * v.w;
  }
  float4 o; o.x = r0; o.y = r1; o.z = r2; o.w = r3;
  *(float4*)(out + (size_t)t * DD + tid * 4) = o;
}

// ---------------------------------------------------------------------------
// Kernel 7: aux loss
// ---------------------------------------------------------------------------
__global__ __launch_bounds__(64)
void k_loss(const float* __restrict__ dens, float* __restrict__ out_loss)
{
  const int lane = threadIdx.x;            // 64 = B*E pairs
  float v = (dens[lane] * (1.f / 2048.f)) * (dens[64 + lane] * (1.f / 2048.f));
#pragma unroll
  for (int off = 32; off >= 1; off >>= 1) v += __shfl_xor(v, off);
  if (lane == 0) out_loss[0] = (v / 64.f) * 256.f * 0.01f;
}

// ---------------------------------------------------------------------------
extern "C" void kernel_launch(void* const* d_in, const int* in_sizes, int n_in,
                              void* d_out, int out_size, void* d_ws, size_t ws_size,
                              hipStream_t stream)
{
  const float* x     = (const float*)d_in[0];
  const float* wgate = (const float*)d_in[1];
  const float* w1    = (const float*)d_in[2];
  const float* w2    = (const float*)d_in[3];
  const float* noise = (const float*)d_in[4];
  float* out = (float*)d_out;

  size_t off = 0;
  char* wsb = (char*)d_ws;
  auto alloc = [&](size_t bytes) -> void* {
    void* p = wsb + off;
    off += (bytes + 255) & ~(size_t)255;
    return p;
  };
  ushort* ei  = (ushort*)alloc((size_t)EE * MROWS * DD * 2);   // 20 MB
  ushort* hid = (ushort*)alloc((size_t)EE * MROWS * HH * 2);   // 80 MB
  float*  eo  = (float*) alloc((size_t)EE * MROWS * DD * 4);   // 40 MB
  int*   idx1 = (int*)  alloc((size_t)NTOK * 4);
  int*   idx2 = (int*)  alloc((size_t)NTOK * 4);
  float* g1   = (float*)alloc((size_t)NTOK * 4);
  float* g2   = (float*)alloc((size_t)NTOK * 4);
  int*   pos1 = (int*)  alloc((size_t)NTOK * 4);
  int*   pos2 = (int*)  alloc((size_t)NTOK * 4);
  int* slot_tok = (int*)alloc((size_t)EE * BB * CAP * 4);
  float* dens = (float*)alloc(128 * 4);

  hipMemsetAsync(dens, 0, 128 * 4, stream);
  k_gating<<<NTOK / 4, 256, 0, stream>>>(x, wgate, noise, idx1, idx2, g1, g2,
                                         pos1, pos2, dens, dens + 64);
  k_scan<<<BB * EE, 64, 0, stream>>>(idx1, idx2, pos1, pos2, slot_tok);
  k_gather<<<EE * MROWS, 256, 0, stream>>>(x, slot_tok, ei);
  expert_gemm<DD, HH, true ><<<EE * (MROWS / 128) * (HH / 128), 256, 0, stream>>>(ei,  w1, hid, nullptr);
  expert_gemm<HH, DD, false><<<EE * (MROWS / 128) * (DD / 128), 256, 0, stream>>>(hid, w2, nullptr, eo);
  k_combine<<<NTOK, 256, 0, stream>>>(eo, idx1, idx2, g1, g2, pos1, pos2, out);
  k_loss<<<1, 64, 0, stream>>>(dens, out + (size_t)NTOK * DD);
}